// Round 6
// baseline (839.960 us; speedup 1.0000x reference)
//
#include <hip/hip_runtime.h>
#include <hip/hip_cooperative_groups.h>

namespace cg = cooperative_groups;

#define N_NODES  50000
#define N_EDGES  1600000
#define NODE_DIM 1024
#define HID      128
#define LN_EPS   1e-5f
#define NBUCK    196              // dst>>8 buckets (256 nodes each)
#define SHARD    6250             // N_EDGES / 256
#define PSTRIPS  1568             // 50176/32 proj strips

typedef float f32x4 __attribute__((ext_vector_type(4)));
typedef __bf16 bf16x8 __attribute__((ext_vector_type(8)));
typedef unsigned short u16x8 __attribute__((ext_vector_type(8)));
typedef unsigned int u32x4 __attribute__((ext_vector_type(4)));

__device__ __forceinline__ unsigned short f2bf(float f) {
  __bf16 b = (__bf16)f;
  return __builtin_bit_cast(unsigned short, b);
}
__device__ __forceinline__ unsigned int pkbf(float a, float b) {
  return (unsigned int)f2bf(a) | ((unsigned int)f2bf(b) << 16);
}
__device__ __forceinline__ float bf2f(unsigned short v) {
  return __uint_as_float((unsigned int)v << 16);
}

__device__ __forceinline__ int scan256_excl(int v, int buf[2][256], int t) {
  int cur = 0;
  buf[0][t] = v;
  __syncthreads();
  for (int off = 1; off < 256; off <<= 1) {
    int nxt = cur ^ 1;
    int s = buf[cur][t];
    if (t >= off) s += buf[cur][t - off];
    buf[nxt][t] = s;
    cur = nxt;
    __syncthreads();
  }
  return buf[cur][t] - v;
}

// ---------------------------------------------------------------------------
// K0: weight convert+PACK (fragment-ordered bf16) + zero accum
// ---------------------------------------------------------------------------
__global__ __launch_bounds__(256) void k_wpack(const float* __restrict__ w,
                                               unsigned short* __restrict__ wp,
                                               float* __restrict__ accum) {
  if (blockIdx.x == 0 && threadIdx.x < HID) accum[threadIdx.x] = 0.f;
  int idx = blockIdx.x * 256 + threadIdx.x;   // 0..16383
  int lane = idx & 63;
  int n = (idx >> 6) & 7;
  int ks = idx >> 9;                          // 0..31
  int fr = lane & 15, kg = lane >> 4;
  const float* src = w + (size_t)(n * 16 + fr) * NODE_DIM + ks * 32 + kg * 8;
  float4 v0 = *(const float4*)(src);
  float4 v1 = *(const float4*)(src + 4);
  unsigned int* o = (unsigned int*)(wp + (size_t)idx * 8);
  o[0] = pkbf(v0.x, v0.y);
  o[1] = pkbf(v0.z, v0.w);
  o[2] = pkbf(v1.x, v1.y);
  o[3] = pkbf(v1.z, v1.w);
}

// ---------------------------------------------------------------------------
// Shared proj strip body (R4's proven barrier-free register MFMA)
// ---------------------------------------------------------------------------
__device__ __forceinline__ void proj_strip(const float* __restrict__ x,
                                           const unsigned short* __restrict__ wp,
                                           const float* __restrict__ pb,
                                           unsigned short* __restrict__ h,
                                           int strip, int lane) {
  const int fr = lane & 15, kg = lane >> 4;
  const int m0s = strip * 32;
  int r0 = m0s + fr;      if (r0 >= N_NODES) r0 = N_NODES - 1;
  int r1 = m0s + 16 + fr; if (r1 >= N_NODES) r1 = N_NODES - 1;
  const float* a0p = x + (size_t)r0 * NODE_DIM + kg * 8;
  const float* a1p = x + (size_t)r1 * NODE_DIM + kg * 8;
  const bf16x8* bp = (const bf16x8*)wp + lane;
  f32x4 acc[2][8] = {};
  float4 xa0, xa1, xa2, xa3, ya0, ya1, ya2, ya3;

#define LOADA_X(KS) { const float* p0 = a0p + (KS) * 32; const float* p1 = a1p + (KS) * 32; \
  xa0 = *(const float4*)p0; xa1 = *(const float4*)(p0 + 4); \
  xa2 = *(const float4*)p1; xa3 = *(const float4*)(p1 + 4); }
#define LOADA_Y(KS) { const float* p0 = a0p + (KS) * 32; const float* p1 = a1p + (KS) * 32; \
  ya0 = *(const float4*)p0; ya1 = *(const float4*)(p0 + 4); \
  ya2 = *(const float4*)p1; ya3 = *(const float4*)(p1 + 4); }
#define COMPUTE(A0, A1, A2, A3, KS) { \
  bf16x8 bfv[8]; \
  _Pragma("unroll") \
  for (int n = 0; n < 8; n++) bfv[n] = bp[((KS) * 8 + n) * 64]; \
  u32x4 pa0, pa1; \
  pa0[0] = pkbf(A0.x, A0.y); pa0[1] = pkbf(A0.z, A0.w); \
  pa0[2] = pkbf(A1.x, A1.y); pa0[3] = pkbf(A1.z, A1.w); \
  pa1[0] = pkbf(A2.x, A2.y); pa1[1] = pkbf(A2.z, A2.w); \
  pa1[2] = pkbf(A3.x, A3.y); pa1[3] = pkbf(A3.z, A3.w); \
  bf16x8 af0 = __builtin_bit_cast(bf16x8, pa0); \
  bf16x8 af1 = __builtin_bit_cast(bf16x8, pa1); \
  _Pragma("unroll") \
  for (int n = 0; n < 8; n++) { \
    acc[0][n] = __builtin_amdgcn_mfma_f32_16x16x32_bf16(af0, bfv[n], acc[0][n], 0, 0, 0); \
    acc[1][n] = __builtin_amdgcn_mfma_f32_16x16x32_bf16(af1, bfv[n], acc[1][n], 0, 0, 0); \
  } }

  LOADA_X(0);
  for (int ks = 0; ks < 32; ks += 2) {
    LOADA_Y(ks + 1);
    COMPUTE(xa0, xa1, xa2, xa3, ks);
    if (ks + 2 < 32) LOADA_X(ks + 2);
    COMPUTE(ya0, ya1, ya2, ya3, ks + 1);
  }
#undef LOADA_X
#undef LOADA_Y
#undef COMPUTE

  const int cr = (lane >> 4) * 4, cc = lane & 15;
#pragma unroll
  for (int n = 0; n < 8; n++) {
    const int col = n * 16 + cc;
    const float bias = pb[col];
#pragma unroll
    for (int m = 0; m < 2; m++) {
      const int rowb = m0s + m * 16 + cr;
#pragma unroll
      for (int i = 0; i < 4; i++) {
        float v = acc[m][n][i] + bias;
        h[(size_t)(rowb + i) * HID + col] = f2bf(v > 0.f ? v : 0.f);
      }
    }
  }
}

// ---------------------------------------------------------------------------
// K_MEGA: whole pipeline, ONE cooperative dispatch. All cross-block sync is
// grid.sync(); every sub-phase is the proven split-kernel logic, grid-strided.
// LDS arena 18.4 KB (T3 aliased over As/Bs) -> 2 blocks/CU at 36.9 KB.
// ---------------------------------------------------------------------------
__global__ __launch_bounds__(256, 2) void k_mega(
    const float* __restrict__ x, const int* __restrict__ ei,
    const unsigned short* __restrict__ wp, const float* __restrict__ pb,
    const float* __restrict__ wl, const float* __restrict__ lb,
    const float* __restrict__ wr, const float* __restrict__ lg,
    const float* __restrict__ lbt, const float* __restrict__ ow,
    const float* __restrict__ ob,
    unsigned short* __restrict__ h, unsigned short* __restrict__ mn,
    unsigned int* __restrict__ bs, unsigned short* __restrict__ nbr,
    int* __restrict__ counts, int* __restrict__ basem,
    int* __restrict__ btot, int* __restrict__ bstart,
    int* __restrict__ offs, int* __restrict__ deg,
    float* __restrict__ accum, float* __restrict__ out) {
  __shared__ __align__(16) unsigned char arena[18432];
  const int tid = threadIdx.x;
  const int wave = tid >> 6, lane = tid & 63;
  const int nb = gridDim.x;
  cg::grid_group grid = cg::this_grid();

  // ---- A: hist ----
  {
    int* bins = (int*)arena;
    for (int vb = blockIdx.x; vb < 256; vb += nb) {
      if (tid < NBUCK) bins[tid] = 0;
      __syncthreads();
      const int base = vb * SHARD;
      for (int i = tid; i < SHARD; i += 256)
        atomicAdd(&bins[ei[N_EDGES + base + i] >> 8], 1);
      __syncthreads();
      if (tid < NBUCK) counts[tid * 256 + vb] = bins[tid];
      __syncthreads();
    }
  }
  grid.sync();
  // ---- B: s1 (per-bucket scan over 256 shard counts) ----
  {
    int(*buf)[256] = (int(*)[256])arena;
    for (int vb = blockIdx.x; vb < NBUCK; vb += nb) {
      __syncthreads();
      int v = counts[vb * 256 + tid];
      int excl = scan256_excl(v, buf, tid);
      basem[vb * 256 + tid] = excl;
      if (tid == 255) btot[vb] = excl + v;
    }
  }
  grid.sync();
  // ---- C: s2 (block 0 scans bucket totals) ----
  if (blockIdx.x == 0) {
    int(*buf)[256] = (int(*)[256])arena;
    int v = (tid < NBUCK) ? btot[tid] : 0;
    int excl = scan256_excl(v, buf, tid);
    if (tid < NBUCK) bstart[tid] = excl;
    if (tid == 0) bstart[NBUCK] = N_EDGES;
  }
  grid.sync();
  // ---- D: scatter ----
  {
    int* cur = (int*)arena;
    for (int vb = blockIdx.x; vb < 256; vb += nb) {
      if (tid < NBUCK) cur[tid] = bstart[tid] + basem[tid * 256 + vb];
      __syncthreads();
      const int base = vb * SHARD;
      for (int i = tid; i < SHARD; i += 256) {
        int e = base + i;
        unsigned int src = (unsigned int)ei[e];
        unsigned int dst = (unsigned int)ei[N_EDGES + e];
        int pos = atomicAdd(&cur[dst >> 8], 1);
        bs[pos] = src | ((dst & 255u) << 16);
      }
      __syncthreads();
    }
  }
  grid.sync();
  // ---- E: per-bucket exact CSR ----
  {
    int* bbins = (int*)arena;
    int(*buf)[256] = (int(*)[256])(arena + 1024);
    int* curs = (int*)(arena + 3072);
    for (int q = blockIdx.x; q < NBUCK; q += nb) {
      int s0 = bstart[q], e0 = bstart[q + 1];
      __syncthreads();
      bbins[tid] = 0;
      __syncthreads();
      for (int i = s0 + tid; i < e0; i += 256)
        atomicAdd(&bbins[(bs[i] >> 16) & 255u], 1);
      __syncthreads();
      int v = bbins[tid];
      int excl = scan256_excl(v, buf, tid);
      int node = q * 256 + tid;
      deg[node] = v;
      offs[node] = s0 + excl;
      curs[tid] = s0 + excl;
      __syncthreads();
      for (int i = s0 + tid; i < e0; i += 256) {
        unsigned int p = bs[i];
        int pos = atomicAdd(&curs[(p >> 16) & 255u], 1);
        nbr[pos] = (unsigned short)(p & 0xffffu);
      }
    }
  }
  grid.sync();
  // ---- F: proj (independent of CSR; serial here for simplicity) ----
  for (int b4 = blockIdx.x; b4 < PSTRIPS / 4; b4 += nb)
    proj_strip(x, wp, pb, h, b4 * 4 + wave, lane);
  grid.sync();
  // ---- G: gather (4-deep ILP) ----
  {
    const int g = lane >> 4, li = lane & 15;
    const int nb4 = nb * 4;
    for (int node = blockIdx.x * 4 + wave; node < N_NODES; node += nb4) {
      const int d = deg[node];
      const int st = offs[node];
      float a[8] = {0.f, 0.f, 0.f, 0.f, 0.f, 0.f, 0.f, 0.f};
      int n = g;
      for (; n + 12 < d; n += 16) {
        int s0 = nbr[st + n];
        int s1 = nbr[st + n + 4];
        int s2 = nbr[st + n + 8];
        int s3 = nbr[st + n + 12];
        u16x8 v0 = *(const u16x8*)(h + (size_t)s0 * HID + li * 8);
        u16x8 v1 = *(const u16x8*)(h + (size_t)s1 * HID + li * 8);
        u16x8 v2 = *(const u16x8*)(h + (size_t)s2 * HID + li * 8);
        u16x8 v3 = *(const u16x8*)(h + (size_t)s3 * HID + li * 8);
#pragma unroll
        for (int k = 0; k < 8; k++)
          a[k] += (bf2f(v0[k]) + bf2f(v1[k])) + (bf2f(v2[k]) + bf2f(v3[k]));
      }
      for (; n < d; n += 4) {
        int s0 = nbr[st + n];
        u16x8 v0 = *(const u16x8*)(h + (size_t)s0 * HID + li * 8);
#pragma unroll
        for (int k = 0; k < 8; k++) a[k] += bf2f(v0[k]);
      }
#pragma unroll
      for (int k = 0; k < 8; k++) {
        a[k] += __shfl_xor(a[k], 16);
        a[k] += __shfl_xor(a[k], 32);
      }
      if (g == 0) {
        float inv = 1.f / fmaxf((float)d, 1.f);
        u16x8 r;
#pragma unroll
        for (int k = 0; k < 8; k++) r[k] = f2bf(a[k] * inv);
        *(u16x8*)(mn + (size_t)node * HID + li * 8) = r;
      }
    }
  }
  grid.sync();
  // ---- H: sage (T3 aliases As/Bs; red at +16K) ----
  {
    unsigned short* As = (unsigned short*)arena;           // 8 KB (k-loop)
    unsigned short* Bs = (unsigned short*)(arena + 8192);  // 8 KB (k-loop)
    float* T3 = (float*)arena;                             // 16 KB (epilogue)
    float* red = (float*)(arena + 16384);                  // 2 KB
    const int wm = (wave >> 1) * 64, wn = (wave & 1) * 64;
    const int srow = tid >> 1, scol = (tid & 1) * 16;
    const int sfr = lane & 15, sko = (lane >> 4) * 8;
    const int cr = (lane >> 4) * 4, cc = lane & 15;
    const int pq = wave >> 1;
    const float g0 = lg[lane], g1 = lg[lane + 64];
    const float t0 = lbt[lane], t1 = lbt[lane + 64];
    const int nt = (N_NODES + 127) / 128;   // 391
    for (int tile = blockIdx.x; tile < nt; tile += nb) {
      const int m0 = tile * 128;
      f32x4 acc[4][4] = {};
      for (int k0 = 0; k0 < 2 * HID; k0 += 32) {
        const unsigned short* baseA = (k0 < HID) ? mn : h;
        const float* baseB = (k0 < HID) ? wl : wr;
        const int kk = (k0 & (HID - 1)) + scol;
        const int arow = m0 + srow;
        u16x8 a0v = {0, 0, 0, 0, 0, 0, 0, 0}, a1v = a0v;
        if (arow < N_NODES) {
          const u16x8* p = (const u16x8*)(baseA + (size_t)arow * HID + kk);
          a0v = p[0]; a1v = p[1];
        }
        const float4* q4 = (const float4*)(baseB + (size_t)srow * HID + kk);
        float4 b0 = q4[0], b1 = q4[1], b2 = q4[2], b3 = q4[3];
        __syncthreads();
        *(u16x8*)&As[srow * 32 + scol] = a0v;
        *(u16x8*)&As[srow * 32 + scol + 8] = a1v;
        unsigned int* db = (unsigned int*)&Bs[srow * 32 + scol];
        db[0] = pkbf(b0.x, b0.y); db[1] = pkbf(b0.z, b0.w);
        db[2] = pkbf(b1.x, b1.y); db[3] = pkbf(b1.z, b1.w);
        db[4] = pkbf(b2.x, b2.y); db[5] = pkbf(b2.z, b2.w);
        db[6] = pkbf(b3.x, b3.y); db[7] = pkbf(b3.z, b3.w);
        __syncthreads();
        bf16x8 af[4], bfr[4];
#pragma unroll
        for (int m = 0; m < 4; m++)
          af[m] = *(const bf16x8*)&As[(wm + m * 16 + sfr) * 32 + sko];
#pragma unroll
        for (int n2 = 0; n2 < 4; n2++)
          bfr[n2] = *(const bf16x8*)&Bs[(wn + n2 * 16 + sfr) * 32 + sko];
#pragma unroll
        for (int m = 0; m < 4; m++)
#pragma unroll
          for (int n2 = 0; n2 < 4; n2++)
            acc[m][n2] = __builtin_amdgcn_mfma_f32_16x16x32_bf16(af[m], bfr[n2], acc[m][n2], 0, 0, 0);
      }
      float ax = 0.f, ay = 0.f;
#pragma unroll
      for (int m = 0; m < 4; m++) {
        __syncthreads();
#pragma unroll
        for (int n2 = 0; n2 < 4; n2++) {
          const int col = wn + n2 * 16 + cc;
          const float bias = lb[col];
#pragma unroll
          for (int i = 0; i < 4; i++)
            T3[(pq * 16 + cr + i) * 128 + col] = acc[m][n2][i] + bias;
        }
        __syncthreads();
        for (int r8 = 0; r8 < 8; r8++) {
          int q8 = wave * 8 + r8;
          int grow = m0 + (q8 >> 4) * 64 + m * 16 + (q8 & 15);
          float v0 = T3[q8 * 128 + lane];
          float v1 = T3[q8 * 128 + lane + 64];
          float sum = v0 + v1, ss = v0 * v0 + v1 * v1;
#pragma unroll
          for (int off = 32; off > 0; off >>= 1) {
            sum += __shfl_xor(sum, off);
            ss += __shfl_xor(ss, off);
          }
          float mu = sum * (1.f / HID);
          float var = ss * (1.f / HID) - mu * mu;
          float rinv = rsqrtf(var + LN_EPS);
          if (grow < N_NODES) {
            float y0 = (v0 - mu) * rinv * g0 + t0;
            float y1 = (v1 - mu) * rinv * g1 + t1;
            ax += fmaxf(y0, 0.f);
            ay += fmaxf(y1, 0.f);
          }
        }
      }
      red[wave * 128 + lane] = ax;
      red[wave * 128 + lane + 64] = ay;
      __syncthreads();
      if (wave == 0) {
        float aa = red[0 * 128 + lane] + red[1 * 128 + lane] +
                   red[2 * 128 + lane] + red[3 * 128 + lane];
        float bb = red[0 * 128 + lane + 64] + red[1 * 128 + lane + 64] +
                   red[2 * 128 + lane + 64] + red[3 * 128 + lane + 64];
        atomicAdd(&accum[lane], aa);
        atomicAdd(&accum[lane + 64], bb);
      }
      __syncthreads();
    }
  }
  grid.sync();
  // ---- I: final ----
  if (blockIdx.x == 0) {
    float* gs = (float*)arena;
    if (tid < HID) gs[tid] = accum[tid] * (1.f / N_NODES);
    __syncthreads();
    if (tid < HID) {
      float s = ob[tid];
      for (int k = 0; k < HID; k++) s += gs[k] * ow[tid * HID + k];
      out[tid] = s;
    }
  }
}

// ===========================================================================
// Fallback split kernels (proven R4 path) — used if cooperative launch fails
// ===========================================================================
__global__ __launch_bounds__(256, 3) void k_proj(const float* __restrict__ x,
                                                 const unsigned short* __restrict__ wp,
                                                 const float* __restrict__ pb,
                                                 unsigned short* __restrict__ h) {
  proj_strip(x, wp, pb, h, blockIdx.x * 4 + (threadIdx.x >> 6), threadIdx.x & 63);
}

__global__ __launch_bounds__(256) void k_hist(const int* __restrict__ ei,
                                              int* __restrict__ counts) {
  __shared__ int bins[NBUCK];
  int t = threadIdx.x;
  if (t < NBUCK) bins[t] = 0;
  __syncthreads();
  int base = blockIdx.x * SHARD;
  for (int i = t; i < SHARD; i += 256)
    atomicAdd(&bins[ei[N_EDGES + base + i] >> 8], 1);
  __syncthreads();
  if (t < NBUCK) counts[t * 256 + blockIdx.x] = bins[t];
}

__global__ __launch_bounds__(256) void k_s1(const int* __restrict__ counts,
                                            int* __restrict__ basem,
                                            int* __restrict__ btot) {
  __shared__ int buf[2][256];
  int t = threadIdx.x, b = blockIdx.x;
  int v = counts[b * 256 + t];
  int excl = scan256_excl(v, buf, t);
  basem[b * 256 + t] = excl;
  if (t == 255) btot[b] = excl + v;
}

__global__ __launch_bounds__(256) void k_s2(const int* __restrict__ btot,
                                            int* __restrict__ bstart,
                                            float* __restrict__ accum) {
  __shared__ int buf[2][256];
  int t = threadIdx.x;
  int v = (t < NBUCK) ? btot[t] : 0;
  int excl = scan256_excl(v, buf, t);
  if (t < NBUCK) bstart[t] = excl;
  if (t == 0) bstart[NBUCK] = N_EDGES;
  if (t < HID) accum[t] = 0.f;
}

__global__ __launch_bounds__(256) void k_scatter(const int* __restrict__ ei,
                                                 const int* __restrict__ basem,
                                                 const int* __restrict__ bstart,
                                                 unsigned int* __restrict__ bs) {
  __shared__ int cur[NBUCK];
  int t = threadIdx.x;
  if (t < NBUCK) cur[t] = bstart[t] + basem[t * 256 + blockIdx.x];
  __syncthreads();
  int base = blockIdx.x * SHARD;
  for (int i = t; i < SHARD; i += 256) {
    int e = base + i;
    unsigned int src = (unsigned int)ei[e];
    unsigned int dst = (unsigned int)ei[N_EDGES + e];
    int pos = atomicAdd(&cur[dst >> 8], 1);
    bs[pos] = src | ((dst & 255u) << 16);
  }
}

__global__ __launch_bounds__(256) void k_bucket(const int* __restrict__ bstart,
                                                const unsigned int* __restrict__ bs,
                                                unsigned short* __restrict__ nbr,
                                                int* __restrict__ offs,
                                                int* __restrict__ deg) {
  __shared__ int bins[256];
  __shared__ int buf[2][256];
  __shared__ int curs[256];
  int t = threadIdx.x, b = blockIdx.x;
  int s = bstart[b], e = bstart[b + 1];
  bins[t] = 0;
  __syncthreads();
  for (int i = s + t; i < e; i += 256)
    atomicAdd(&bins[(bs[i] >> 16) & 255u], 1);
  __syncthreads();
  int v = bins[t];
  int excl = scan256_excl(v, buf, t);
  int node = b * 256 + t;
  deg[node]  = v;
  offs[node] = s + excl;
  curs[t]    = s + excl;
  __syncthreads();
  for (int i = s + t; i < e; i += 256) {
    unsigned int p = bs[i];
    int pos = atomicAdd(&curs[(p >> 16) & 255u], 1);
    nbr[pos] = (unsigned short)(p & 0xffffu);
  }
}

__global__ __launch_bounds__(256) void k_gather(const unsigned short* __restrict__ h,
                                                const unsigned short* __restrict__ nbr,
                                                const int* __restrict__ offs,
                                                const int* __restrict__ deg,
                                                unsigned short* __restrict__ mn) {
  const int wave = threadIdx.x >> 6;
  const int lane = threadIdx.x & 63;
  const int node = blockIdx.x * 4 + wave;
  if (node >= N_NODES) return;
  const int g = lane >> 4, li = lane & 15;
  const int d  = deg[node];
  const int st = offs[node];
  float a[8] = {0.f, 0.f, 0.f, 0.f, 0.f, 0.f, 0.f, 0.f};
  int n = g;
  for (; n + 4 < d; n += 8) {
    int s0 = nbr[st + n];
    int s1 = nbr[st + n + 4];
    u16x8 v0 = *(const u16x8*)(h + (size_t)s0 * HID + li * 8);
    u16x8 v1 = *(const u16x8*)(h + (size_t)s1 * HID + li * 8);
#pragma unroll
    for (int k = 0; k < 8; k++) a[k] += bf2f(v0[k]) + bf2f(v1[k]);
  }
  if (n < d) {
    int s0 = nbr[st + n];
    u16x8 v0 = *(const u16x8*)(h + (size_t)s0 * HID + li * 8);
#pragma unroll
    for (int k = 0; k < 8; k++) a[k] += bf2f(v0[k]);
  }
#pragma unroll
  for (int k = 0; k < 8; k++) {
    a[k] += __shfl_xor(a[k], 16);
    a[k] += __shfl_xor(a[k], 32);
  }
  if (g == 0) {
    float inv = 1.f / fmaxf((float)d, 1.f);
    u16x8 r;
#pragma unroll
    for (int k = 0; k < 8; k++) r[k] = f2bf(a[k] * inv);
    *(u16x8*)(mn + (size_t)node * HID + li * 8) = r;
  }
}

__global__ __launch_bounds__(256) void k_sage(const unsigned short* __restrict__ mn,
                                              const unsigned short* __restrict__ h,
                                              const float* __restrict__ wl,
                                              const float* __restrict__ wr,
                                              const float* __restrict__ lb,
                                              const float* __restrict__ lg,
                                              const float* __restrict__ lbt,
                                              float* __restrict__ accum) {
  __shared__ unsigned short As[128 * 32];
  __shared__ unsigned short Bs[128 * 32];
  __shared__ float T3[32 * 128];
  __shared__ float red[4][128];
  const int tid = threadIdx.x;
  const int m0 = blockIdx.x * 128;
  const int wave = tid >> 6, lane = tid & 63;
  const int wm = (wave >> 1) * 64, wn = (wave & 1) * 64;
  const int srow = tid >> 1, scol = (tid & 1) * 16;
  const int fr = lane & 15, ko = (lane >> 4) * 8;

  f32x4 acc[4][4] = {};

  for (int k0 = 0; k0 < 2 * HID; k0 += 32) {
    const unsigned short* baseA = (k0 < HID) ? mn : h;
    const float* baseB = (k0 < HID) ? wl : wr;
    const int kk = (k0 & (HID - 1)) + scol;
    const int arow = m0 + srow;
    u16x8 a0 = {0, 0, 0, 0, 0, 0, 0, 0}, a1 = a0;
    if (arow < N_NODES) {
      const u16x8* p = (const u16x8*)(baseA + (size_t)arow * HID + kk);
      a0 = p[0]; a1 = p[1];
    }
    const float4* q = (const float4*)(baseB + (size_t)srow * HID + kk);
    float4 b0 = q[0], b1 = q[1], b2 = q[2], b3 = q[3];

    __syncthreads();
    *(u16x8*)&As[srow * 32 + scol]     = a0;
    *(u16x8*)&As[srow * 32 + scol + 8] = a1;
    unsigned int* db = (unsigned int*)&Bs[srow * 32 + scol];
    db[0] = pkbf(b0.x, b0.y); db[1] = pkbf(b0.z, b0.w);
    db[2] = pkbf(b1.x, b1.y); db[3] = pkbf(b1.z, b1.w);
    db[4] = pkbf(b2.x, b2.y); db[5] = pkbf(b2.z, b2.w);
    db[6] = pkbf(b3.x, b3.y); db[7] = pkbf(b3.z, b3.w);
    __syncthreads();

    bf16x8 af[4], bfr[4];
#pragma unroll
    for (int m = 0; m < 4; m++)
      af[m] = *(const bf16x8*)&As[(wm + m * 16 + fr) * 32 + ko];
#pragma unroll
    for (int n = 0; n < 4; n++)
      bfr[n] = *(const bf16x8*)&Bs[(wn + n * 16 + fr) * 32 + ko];
#pragma unroll
    for (int m = 0; m < 4; m++)
#pragma unroll
      for (int n = 0; n < 4; n++)
        acc[m][n] = __builtin_amdgcn_mfma_f32_16x16x32_bf16(af[m], bfr[n], acc[m][n], 0, 0, 0);
  }

  const int cr = (lane >> 4) * 4, cc = lane & 15;
  const int p = wave >> 1;
  const float g0 = lg[lane], g1 = lg[lane + 64];
  const float t0 = lbt[lane], t1 = lbt[lane + 64];
  float ax = 0.f, ay = 0.f;
#pragma unroll
  for (int m = 0; m < 4; m++) {
    __syncthreads();
#pragma unroll
    for (int n = 0; n < 4; n++) {
      const int col = wn + n * 16 + cc;
      const float bias = lb[col];
#pragma unroll
      for (int i = 0; i < 4; i++)
        T3[(p * 16 + cr + i) * 128 + col] = acc[m][n][i] + bias;
    }
    __syncthreads();
    for (int r8 = 0; r8 < 8; r8++) {
      int q8 = wave * 8 + r8;
      int grow = m0 + (q8 >> 4) * 64 + m * 16 + (q8 & 15);
      float v0 = T3[q8 * 128 + lane];
      float v1 = T3[q8 * 128 + lane + 64];
      float sum = v0 + v1, ss = v0 * v0 + v1 * v1;
#pragma unroll
      for (int off = 32; off > 0; off >>= 1) {
        sum += __shfl_xor(sum, off);
        ss  += __shfl_xor(ss, off);
      }
      float mu  = sum * (1.f / HID);
      float var = ss * (1.f / HID) - mu * mu;
      float rinv = rsqrtf(var + LN_EPS);
      if (grow < N_NODES) {
        float y0 = (v0 - mu) * rinv * g0 + t0;
        float y1 = (v1 - mu) * rinv * g1 + t1;
        ax += fmaxf(y0, 0.f);
        ay += fmaxf(y1, 0.f);
      }
    }
  }
  red[wave][lane]      = ax;
  red[wave][lane + 64] = ay;
  __syncthreads();
  if (wave == 0) {
    float a  = red[0][lane] + red[1][lane] + red[2][lane] + red[3][lane];
    float bb = red[0][lane + 64] + red[1][lane + 64] + red[2][lane + 64] + red[3][lane + 64];
    atomicAdd(&accum[lane], a);
    atomicAdd(&accum[lane + 64], bb);
  }
}

__global__ __launch_bounds__(128) void k_final(const float* __restrict__ accum,
                                               const float* __restrict__ ow,
                                               const float* __restrict__ ob,
                                               float* __restrict__ out) {
  __shared__ float gs[HID];
  int t = threadIdx.x;
  gs[t] = accum[t] * (1.f / N_NODES);
  __syncthreads();
  float s = ob[t];
  for (int k = 0; k < HID; k++) s += gs[k] * ow[t * HID + k];
  out[t] = s;
}

// ---------------------------------------------------------------------------
extern "C" void kernel_launch(void* const* d_in, const int* in_sizes, int n_in,
                              void* d_out, int out_size, void* d_ws, size_t ws_size,
                              hipStream_t stream) {
  const float* x   = (const float*)d_in[0];
  const int*   ei  = (const int*)d_in[1];
  const float* pw  = (const float*)d_in[2];
  const float* pb  = (const float*)d_in[3];
  const float* wl  = (const float*)d_in[4];
  const float* lb  = (const float*)d_in[5];
  const float* wr  = (const float*)d_in[6];
  const float* lg  = (const float*)d_in[7];
  const float* lbt = (const float*)d_in[8];
  const float* ow  = (const float*)d_in[9];
  const float* ob  = (const float*)d_in[10];
  float* out = (float*)d_out;

  const int PAD = NBUCK * 256;  // 50176
  unsigned short* h  = (unsigned short*)d_ws;                   // PAD*128 bf16
  unsigned short* mn = h + (size_t)PAD * HID;                   // PAD*128 bf16
  unsigned int* bsp  = (unsigned int*)(mn + (size_t)PAD * HID); // E packed u32
  unsigned short* nbr = (unsigned short*)(bsp + N_EDGES);       // E u16
  int* counts = (int*)(nbr + N_EDGES);                          // NBUCK*256
  int* basem  = counts + NBUCK * 256;
  int* btot   = basem + NBUCK * 256;                            // 256
  int* bstart = btot + 256;                                     // 256 (+1 used)
  int* offs   = bstart + 256;                                   // PAD
  int* deg    = offs + PAD;                                     // PAD
  float* accum = (float*)(deg + PAD);                           // 128
  unsigned short* wp = (unsigned short*)(accum + 128);          // HID*NODE_DIM bf16 packed

  hipLaunchKernelGGL(k_wpack, dim3(64), dim3(256), 0, stream, pw, wp, accum);

  // decide cooperative grid once (occupancy query is capture-safe)
  static int coop_grid = -1;
  if (coop_grid < 0) {
    int occ = 0;
    hipError_t oe = hipOccupancyMaxActiveBlocksPerMultiprocessor(&occ, k_mega, 256, 0);
    coop_grid = (oe == hipSuccess && occ >= 1) ? ((occ >= 2 ? 2 : 1) * 256) : 0;
  }

  bool done = false;
  if (coop_grid > 0) {
    void* kargs[] = {
      (void*)&x, (void*)&ei, (void*)&wp, (void*)&pb, (void*)&wl, (void*)&lb,
      (void*)&wr, (void*)&lg, (void*)&lbt, (void*)&ow, (void*)&ob,
      (void*)&h, (void*)&mn, (void*)&bsp, (void*)&nbr,
      (void*)&counts, (void*)&basem, (void*)&btot, (void*)&bstart,
      (void*)&offs, (void*)&deg, (void*)&accum, (void*)&out
    };
    hipError_t err = hipLaunchCooperativeKernel((void*)k_mega, dim3(coop_grid),
                                                dim3(256), kargs, 0, stream);
    done = (err == hipSuccess);
    if (!done) coop_grid = 0;   // stop retrying in later captures
  }

  if (!done) {
    // proven R4 split path
    const int MB = (N_NODES + 127) / 128;
    hipLaunchKernelGGL(k_hist,    dim3(256),   dim3(256), 0, stream, ei, counts);
    hipLaunchKernelGGL(k_s1,      dim3(NBUCK), dim3(256), 0, stream, counts, basem, btot);
    hipLaunchKernelGGL(k_s2,      dim3(1),     dim3(256), 0, stream, btot, bstart, accum);
    hipLaunchKernelGGL(k_scatter, dim3(256),   dim3(256), 0, stream, ei, basem, bstart, bsp);
    hipLaunchKernelGGL(k_bucket,  dim3(NBUCK), dim3(256), 0, stream, bstart, bsp, nbr, offs, deg);
    hipLaunchKernelGGL(k_proj,    dim3(392),   dim3(256), 0, stream, x, wp, pb, h);
    hipLaunchKernelGGL(k_gather,  dim3((N_NODES + 3) / 4), dim3(256), 0, stream, h, nbr, offs, deg, mn);
    hipLaunchKernelGGL(k_sage,    dim3(MB),    dim3(256), 0, stream, mn, h, wl, wr, lb, lg, lbt, accum);
    hipLaunchKernelGGL(k_final,   dim3(1),     dim3(128), 0, stream, accum, ow, ob, out);
  }
}

// Round 7
// 619.170 us; speedup vs baseline: 1.3566x; 1.3566x over previous
//
#include <hip/hip_runtime.h>

#define N_NODES  50000
#define N_EDGES  1600000
#define NODE_DIM 1024
#define HID      128
#define LN_EPS   1e-5f
#define NBUCK    196              // node>>8 buckets (256 nodes each)
#define PAD      (NBUCK * 256)    // 50176
#define PSTRIPS  1568             // PAD/32 strips

typedef float f32x4 __attribute__((ext_vector_type(4)));
typedef __bf16 bf16x8 __attribute__((ext_vector_type(8)));
typedef unsigned short u16x8 __attribute__((ext_vector_type(8)));
typedef unsigned int u32x4 __attribute__((ext_vector_type(4)));

__device__ __forceinline__ unsigned short f2bf(float f) {
  __bf16 b = (__bf16)f;
  return __builtin_bit_cast(unsigned short, b);
}
__device__ __forceinline__ unsigned int pkbf(float a, float b) {
  return (unsigned int)f2bf(a) | ((unsigned int)f2bf(b) << 16);
}
__device__ __forceinline__ float bf2f(unsigned short v) {
  return __uint_as_float((unsigned int)v << 16);
}

__device__ __forceinline__ int scan256_excl(int v, int buf[2][256], int t) {
  int cur = 0;
  buf[0][t] = v;
  __syncthreads();
  for (int off = 1; off < 256; off <<= 1) {
    int nxt = cur ^ 1;
    int s = buf[cur][t];
    if (t >= off) s += buf[cur][t - off];
    buf[nxt][t] = s;
    cur = nxt;
    __syncthreads();
  }
  return buf[cur][t] - v;
}

// ---------------------------------------------------------------------------
// K_WSPACK: pack sage weights B=[wl|wr] (128 x 256) into fragment order
//   wsp[((ks*8+n)*64+lane)*8+j] = B[n*16+(lane&15)][ks*32+(lane>>4)*8+j]
// Also zeroes deg[] and accum[] (must run before k_deg / k_sage).
// ---------------------------------------------------------------------------
__global__ __launch_bounds__(256) void k_wspack(const float* __restrict__ wl,
                                                const float* __restrict__ wr,
                                                unsigned short* __restrict__ wsp,
                                                int* __restrict__ deg,
                                                float* __restrict__ accum) {
  int idx = blockIdx.x * 256 + threadIdx.x;     // 0..4095
  // zero deg (PAD ints = 12544 int4) and accum
  int4* d4 = (int4*)deg;
  for (int j = idx; j < PAD / 4; j += 4096) d4[j] = make_int4(0, 0, 0, 0);
  if (idx < HID) accum[idx] = 0.f;

  int lane = idx & 63;
  int n = (idx >> 6) & 7;
  int ks = idx >> 9;                            // 0..7
  int fr = lane & 15, kg = lane >> 4;
  int row = n * 16 + fr;
  int k0 = ks * 32 + kg * 8;
  const float* src = (k0 < HID) ? (wl + (size_t)row * HID + k0)
                                : (wr + (size_t)row * HID + (k0 - HID));
  float4 v0 = *(const float4*)(src);
  float4 v1 = *(const float4*)(src + 4);
  unsigned int* o = (unsigned int*)(wsp + (size_t)idx * 8);
  o[0] = pkbf(v0.x, v0.y);
  o[1] = pkbf(v0.z, v0.w);
  o[2] = pkbf(v1.x, v1.y);
  o[3] = pkbf(v1.z, v1.w);
}

// ---------------------------------------------------------------------------
// K_WPACK: pack proj weights (128 x 1024) into fragment order (R4, proven)
// ---------------------------------------------------------------------------
__global__ __launch_bounds__(256) void k_wpack(const float* __restrict__ w,
                                               unsigned short* __restrict__ wp) {
  int idx = blockIdx.x * 256 + threadIdx.x;   // 0..16383
  int lane = idx & 63;
  int n = (idx >> 6) & 7;
  int ks = idx >> 9;                          // 0..31
  int fr = lane & 15, kg = lane >> 4;
  const float* src = w + (size_t)(n * 16 + fr) * NODE_DIM + ks * 32 + kg * 8;
  float4 v0 = *(const float4*)(src);
  float4 v1 = *(const float4*)(src + 4);
  unsigned int* o = (unsigned int*)(wp + (size_t)idx * 8);
  o[0] = pkbf(v0.x, v0.y);
  o[1] = pkbf(v0.z, v0.w);
  o[2] = pkbf(v1.x, v1.y);
  o[3] = pkbf(v1.z, v1.w);
}

// ---------------------------------------------------------------------------
// Direct-atomic CSR: deg -> scan1 -> scan2 -> curinit -> fill
// ---------------------------------------------------------------------------
__global__ __launch_bounds__(256) void k_deg(const int* __restrict__ ei,
                                             int* __restrict__ deg) {
  int t = blockIdx.x * 256 + threadIdx.x;
  for (int e = t; e < N_EDGES; e += gridDim.x * 256)
    atomicAdd(&deg[ei[N_EDGES + e]], 1);
}

__global__ __launch_bounds__(256) void k_scan1(const int* __restrict__ deg,
                                               int* __restrict__ offs,
                                               int* __restrict__ btot) {
  __shared__ int buf[2][256];
  int t = threadIdx.x, b = blockIdx.x;
  int v = deg[b * 256 + t];
  int excl = scan256_excl(v, buf, t);
  offs[b * 256 + t] = excl;          // partial (within bucket)
  if (t == 255) btot[b] = excl + v;
}

__global__ __launch_bounds__(256) void k_scan2(const int* __restrict__ btot,
                                               int* __restrict__ bstart) {
  __shared__ int buf[2][256];
  int t = threadIdx.x;
  int v = (t < NBUCK) ? btot[t] : 0;
  int excl = scan256_excl(v, buf, t);
  if (t < NBUCK) bstart[t] = excl;
}

__global__ __launch_bounds__(256) void k_curinit(const int* __restrict__ bstart,
                                                 int* __restrict__ offs,
                                                 int* __restrict__ cur) {
  int node = blockIdx.x * 256 + threadIdx.x;
  int o = offs[node] + bstart[node >> 8];
  offs[node] = o;
  cur[node] = o;
}

__global__ __launch_bounds__(256) void k_fill(const int* __restrict__ ei,
                                              int* __restrict__ cur,
                                              unsigned short* __restrict__ nbr) {
  int t = blockIdx.x * 256 + threadIdx.x;
  for (int e = t; e < N_EDGES; e += gridDim.x * 256) {
    int src = ei[e];
    int dst = ei[N_EDGES + e];
    int pos = atomicAdd(&cur[dst], 1);
    nbr[pos] = (unsigned short)src;
  }
}

// ---------------------------------------------------------------------------
// proj strip body (R4, proven): barrier-free register MFMA
// ---------------------------------------------------------------------------
__device__ __forceinline__ void proj_strip(const float* __restrict__ x,
                                           const unsigned short* __restrict__ wp,
                                           const float* __restrict__ pb,
                                           unsigned short* __restrict__ h,
                                           int strip, int lane) {
  const int fr = lane & 15, kg = lane >> 4;
  const int m0s = strip * 32;
  int r0 = m0s + fr;      if (r0 >= N_NODES) r0 = N_NODES - 1;
  int r1 = m0s + 16 + fr; if (r1 >= N_NODES) r1 = N_NODES - 1;
  const float* a0p = x + (size_t)r0 * NODE_DIM + kg * 8;
  const float* a1p = x + (size_t)r1 * NODE_DIM + kg * 8;
  const bf16x8* bp = (const bf16x8*)wp + lane;
  f32x4 acc[2][8] = {};
  float4 xa0, xa1, xa2, xa3, ya0, ya1, ya2, ya3;

#define LOADA_X(KS) { const float* p0 = a0p + (KS) * 32; const float* p1 = a1p + (KS) * 32; \
  xa0 = *(const float4*)p0; xa1 = *(const float4*)(p0 + 4); \
  xa2 = *(const float4*)p1; xa3 = *(const float4*)(p1 + 4); }
#define LOADA_Y(KS) { const float* p0 = a0p + (KS) * 32; const float* p1 = a1p + (KS) * 32; \
  ya0 = *(const float4*)p0; ya1 = *(const float4*)(p0 + 4); \
  ya2 = *(const float4*)p1; ya3 = *(const float4*)(p1 + 4); }
#define COMPUTE(A0, A1, A2, A3, KS) { \
  bf16x8 bfv[8]; \
  _Pragma("unroll") \
  for (int n = 0; n < 8; n++) bfv[n] = bp[((KS) * 8 + n) * 64]; \
  u32x4 pa0, pa1; \
  pa0[0] = pkbf(A0.x, A0.y); pa0[1] = pkbf(A0.z, A0.w); \
  pa0[2] = pkbf(A1.x, A1.y); pa0[3] = pkbf(A1.z, A1.w); \
  pa1[0] = pkbf(A2.x, A2.y); pa1[1] = pkbf(A2.z, A2.w); \
  pa1[2] = pkbf(A3.x, A3.y); pa1[3] = pkbf(A3.z, A3.w); \
  bf16x8 af0 = __builtin_bit_cast(bf16x8, pa0); \
  bf16x8 af1 = __builtin_bit_cast(bf16x8, pa1); \
  _Pragma("unroll") \
  for (int n = 0; n < 8; n++) { \
    acc[0][n] = __builtin_amdgcn_mfma_f32_16x16x32_bf16(af0, bfv[n], acc[0][n], 0, 0, 0); \
    acc[1][n] = __builtin_amdgcn_mfma_f32_16x16x32_bf16(af1, bfv[n], acc[1][n], 0, 0, 0); \
  } }

  LOADA_X(0);
  for (int ks = 0; ks < 32; ks += 2) {
    LOADA_Y(ks + 1);
    COMPUTE(xa0, xa1, xa2, xa3, ks);
    if (ks + 2 < 32) LOADA_X(ks + 2);
    COMPUTE(ya0, ya1, ya2, ya3, ks + 1);
  }
#undef LOADA_X
#undef LOADA_Y
#undef COMPUTE

  const int cr = (lane >> 4) * 4, cc = lane & 15;
#pragma unroll
  for (int n = 0; n < 8; n++) {
    const int col = n * 16 + cc;
    const float bias = pb[col];
#pragma unroll
    for (int m = 0; m < 2; m++) {
      const int rowb = m0s + m * 16 + cr;
#pragma unroll
      for (int i = 0; i < 4; i++) {
        float v = acc[m][n][i] + bias;
        h[(size_t)(rowb + i) * HID + col] = f2bf(v > 0.f ? v : 0.f);
      }
    }
  }
}

__global__ __launch_bounds__(256, 3) void k_proj(const float* __restrict__ x,
                                                 const unsigned short* __restrict__ wp,
                                                 const float* __restrict__ pb,
                                                 unsigned short* __restrict__ h) {
  proj_strip(x, wp, pb, h, blockIdx.x * 4 + (threadIdx.x >> 6), threadIdx.x & 63);
}

// ---------------------------------------------------------------------------
// K_GATHER: mean over neighbors, 4-deep ILP (16 rows in flight per wave).
// Covers PAD nodes (deg 0 -> writes zeros) so sage needs no guards on mn.
// ---------------------------------------------------------------------------
__global__ __launch_bounds__(256) void k_gather(const unsigned short* __restrict__ h,
                                                const unsigned short* __restrict__ nbr,
                                                const int* __restrict__ offs,
                                                const int* __restrict__ deg,
                                                unsigned short* __restrict__ mn) {
  const int wave = threadIdx.x >> 6;
  const int lane = threadIdx.x & 63;
  const int node = blockIdx.x * 4 + wave;        // < PAD by grid
  const int g = lane >> 4, li = lane & 15;
  const int d  = deg[node];
  const int st = offs[node];
  float a[8] = {0.f, 0.f, 0.f, 0.f, 0.f, 0.f, 0.f, 0.f};
  int n = g;
  for (; n + 12 < d; n += 16) {
    int s0 = nbr[st + n];
    int s1 = nbr[st + n + 4];
    int s2 = nbr[st + n + 8];
    int s3 = nbr[st + n + 12];
    u16x8 v0 = *(const u16x8*)(h + (size_t)s0 * HID + li * 8);
    u16x8 v1 = *(const u16x8*)(h + (size_t)s1 * HID + li * 8);
    u16x8 v2 = *(const u16x8*)(h + (size_t)s2 * HID + li * 8);
    u16x8 v3 = *(const u16x8*)(h + (size_t)s3 * HID + li * 8);
#pragma unroll
    for (int k = 0; k < 8; k++)
      a[k] += (bf2f(v0[k]) + bf2f(v1[k])) + (bf2f(v2[k]) + bf2f(v3[k]));
  }
  for (; n < d; n += 4) {
    int s0 = nbr[st + n];
    u16x8 v0 = *(const u16x8*)(h + (size_t)s0 * HID + li * 8);
#pragma unroll
    for (int k = 0; k < 8; k++) a[k] += bf2f(v0[k]);
  }
#pragma unroll
  for (int k = 0; k < 8; k++) {
    a[k] += __shfl_xor(a[k], 16);
    a[k] += __shfl_xor(a[k], 32);
  }
  if (g == 0) {
    float inv = 1.f / fmaxf((float)d, 1.f);
    u16x8 r;
#pragma unroll
    for (int k = 0; k < 8; k++) r[k] = f2bf(a[k] * inv);
    *(u16x8*)(mn + (size_t)node * HID + li * 8) = r;
  }
}

// ---------------------------------------------------------------------------
// K_SAGE (R7 rewrite): barrier-free register MFMA + in-register LayerNorm.
// Per wave: 32 rows of [mn|h] (N x 256) @ packed [wl|wr]^T (+lb), then
// LN via shfl_xor(1,2,4,8) row-reduce, ReLU, pool via shfl_xor(16,32),
// tiny 2KB LDS reduce across the 4 waves, 128 atomics/block.
// ---------------------------------------------------------------------------
__global__ __launch_bounds__(256) void k_sage(const unsigned short* __restrict__ mn,
                                              const unsigned short* __restrict__ h,
                                              const unsigned short* __restrict__ wsp,
                                              const float* __restrict__ lb,
                                              const float* __restrict__ lg,
                                              const float* __restrict__ lbt,
                                              float* __restrict__ accum) {
  __shared__ float red[4][128];
  const int wave = threadIdx.x >> 6, lane = threadIdx.x & 63;
  const int strip = blockIdx.x * 4 + wave;   // 0..PSTRIPS-1
  const int m0s = strip * 32;
  const int fr = lane & 15, kg = lane >> 4;
  const bf16x8* bp = (const bf16x8*)wsp + lane;

  const unsigned short* a0m = mn + (size_t)(m0s + fr) * HID + kg * 8;
  const unsigned short* a1m = mn + (size_t)(m0s + 16 + fr) * HID + kg * 8;
  const unsigned short* a0h = h  + (size_t)(m0s + fr) * HID + kg * 8;
  const unsigned short* a1h = h  + (size_t)(m0s + 16 + fr) * HID + kg * 8;

  f32x4 acc[2][8] = {};
#pragma unroll
  for (int ks = 0; ks < 8; ks++) {
    const unsigned short* s0 = (ks < 4) ? (a0m + ks * 32) : (a0h + (ks - 4) * 32);
    const unsigned short* s1 = (ks < 4) ? (a1m + ks * 32) : (a1h + (ks - 4) * 32);
    bf16x8 af0 = *(const bf16x8*)s0;
    bf16x8 af1 = *(const bf16x8*)s1;
    bf16x8 bfv[8];
#pragma unroll
    for (int n = 0; n < 8; n++) bfv[n] = bp[(ks * 8 + n) * 64];
#pragma unroll
    for (int n = 0; n < 8; n++) {
      acc[0][n] = __builtin_amdgcn_mfma_f32_16x16x32_bf16(af0, bfv[n], acc[0][n], 0, 0, 0);
      acc[1][n] = __builtin_amdgcn_mfma_f32_16x16x32_bf16(af1, bfv[n], acc[1][n], 0, 0, 0);
    }
  }

  const int cr = (lane >> 4) * 4, cc = lane & 15;
  float gv[8], bv[8], lbv[8];
#pragma unroll
  for (int n = 0; n < 8; n++) {
    gv[n]  = lg[n * 16 + cc];
    bv[n]  = lbt[n * 16 + cc];
    lbv[n] = lb[n * 16 + cc];
  }
  float pool[8] = {0.f, 0.f, 0.f, 0.f, 0.f, 0.f, 0.f, 0.f};
#pragma unroll
  for (int m = 0; m < 2; m++) {
#pragma unroll
    for (int i = 0; i < 4; i++) {
      float v[8];
      float sum = 0.f, ss = 0.f;
#pragma unroll
      for (int n = 0; n < 8; n++) {
        v[n] = acc[m][n][i] + lbv[n];
        sum += v[n];
        ss  += v[n] * v[n];
      }
#pragma unroll
      for (int off = 1; off < 16; off <<= 1) {
        sum += __shfl_xor(sum, off);
        ss  += __shfl_xor(ss, off);
      }
      float mu   = sum * (1.f / HID);
      float var  = ss * (1.f / HID) - mu * mu;
      float rinv = rsqrtf(var + LN_EPS);
      int row = m0s + m * 16 + cr + i;
      if (row < N_NODES) {
#pragma unroll
        for (int n = 0; n < 8; n++) {
          float y = (v[n] - mu) * rinv * gv[n] + bv[n];
          pool[n] += fmaxf(y, 0.f);
        }
      }
    }
  }
#pragma unroll
  for (int n = 0; n < 8; n++) {
    pool[n] += __shfl_xor(pool[n], 16);
    pool[n] += __shfl_xor(pool[n], 32);
  }
  if (lane < 16) {
#pragma unroll
    for (int n = 0; n < 8; n++) red[wave][n * 16 + lane] = pool[n];
  }
  __syncthreads();
  if (wave == 0) {
    float s0 = red[0][lane] + red[1][lane] + red[2][lane] + red[3][lane];
    float s1 = red[0][lane + 64] + red[1][lane + 64] + red[2][lane + 64] + red[3][lane + 64];
    atomicAdd(&accum[lane], s0);
    atomicAdd(&accum[lane + 64], s1);
  }
}

// ---------------------------------------------------------------------------
__global__ __launch_bounds__(128) void k_final(const float* __restrict__ accum,
                                               const float* __restrict__ ow,
                                               const float* __restrict__ ob,
                                               float* __restrict__ out) {
  __shared__ float gs[HID];
  int t = threadIdx.x;
  gs[t] = accum[t] * (1.f / N_NODES);
  __syncthreads();
  float s = ob[t];
  for (int k = 0; k < HID; k++) s += gs[k] * ow[t * HID + k];
  out[t] = s;
}

// ---------------------------------------------------------------------------
extern "C" void kernel_launch(void* const* d_in, const int* in_sizes, int n_in,
                              void* d_out, int out_size, void* d_ws, size_t ws_size,
                              hipStream_t stream) {
  const float* x   = (const float*)d_in[0];
  const int*   ei  = (const int*)d_in[1];
  const float* pw  = (const float*)d_in[2];
  const float* pb  = (const float*)d_in[3];
  const float* wl  = (const float*)d_in[4];
  const float* lb  = (const float*)d_in[5];
  const float* wr  = (const float*)d_in[6];
  const float* lg  = (const float*)d_in[7];
  const float* lbt = (const float*)d_in[8];
  const float* ow  = (const float*)d_in[9];
  const float* ob  = (const float*)d_in[10];
  float* out = (float*)d_out;

  unsigned short* h  = (unsigned short*)d_ws;                   // PAD*128 bf16
  unsigned short* mn = h + (size_t)PAD * HID;                   // PAD*128 bf16
  unsigned short* nbr = mn + (size_t)PAD * HID;                 // E u16
  int* deg    = (int*)(nbr + N_EDGES);                          // PAD
  int* offs   = deg + PAD;                                      // PAD
  int* cur    = offs + PAD;                                     // PAD
  int* btot   = cur + PAD;                                      // 256
  int* bstart = btot + 256;                                     // 256
  float* accum = (float*)(bstart + 256);                        // 128
  unsigned short* wp  = (unsigned short*)(accum + 128);         // 128*1024 bf16 packed
  unsigned short* wsp = wp + (size_t)HID * NODE_DIM;            // 128*256 bf16 packed

  hipLaunchKernelGGL(k_wspack,  dim3(16),        dim3(256), 0, stream, wl, wr, wsp, deg, accum);
  hipLaunchKernelGGL(k_wpack,   dim3(64),        dim3(256), 0, stream, pw, wp);
  hipLaunchKernelGGL(k_deg,     dim3(800),       dim3(256), 0, stream, ei, deg);
  hipLaunchKernelGGL(k_scan1,   dim3(NBUCK),     dim3(256), 0, stream, deg, offs, btot);
  hipLaunchKernelGGL(k_scan2,   dim3(1),         dim3(256), 0, stream, btot, bstart);
  hipLaunchKernelGGL(k_curinit, dim3(NBUCK),     dim3(256), 0, stream, bstart, offs, cur);
  hipLaunchKernelGGL(k_fill,    dim3(800),       dim3(256), 0, stream, ei, cur, nbr);
  hipLaunchKernelGGL(k_proj,    dim3(PSTRIPS/4), dim3(256), 0, stream, x, wp, pb, h);
  hipLaunchKernelGGL(k_gather,  dim3(PAD/4),     dim3(256), 0, stream, h, nbr, offs, deg, mn);
  hipLaunchKernelGGL(k_sage,    dim3(PSTRIPS/4), dim3(256), 0, stream, mn, h, wsp, lb, lg, lbt, accum);
  hipLaunchKernelGGL(k_final,   dim3(1),         dim3(128), 0, stream, accum, ow, ob, out);
}

// Round 8
// 464.898 us; speedup vs baseline: 1.8068x; 1.3318x over previous
//
#include <hip/hip_runtime.h>

#define N_NODES  50000
#define N_EDGES  1600000
#define NODE_DIM 1024
#define HID      128
#define LN_EPS   1e-5f
#define NBUCK    196              // dst>>8 buckets (256 nodes each)
#define SHARD    6250             // N_EDGES / 256
#define PAD      (NBUCK * 256)    // 50176
#define PSTRIPS  1568             // PAD/32 strips

typedef float f32x4 __attribute__((ext_vector_type(4)));
typedef __bf16 bf16x8 __attribute__((ext_vector_type(8)));
typedef unsigned short u16x8 __attribute__((ext_vector_type(8)));
typedef unsigned int u32x4 __attribute__((ext_vector_type(4)));

__device__ __forceinline__ unsigned short f2bf(float f) {
  __bf16 b = (__bf16)f;
  return __builtin_bit_cast(unsigned short, b);
}
__device__ __forceinline__ unsigned int pkbf(float a, float b) {
  return (unsigned int)f2bf(a) | ((unsigned int)f2bf(b) << 16);
}
__device__ __forceinline__ float bf2f(unsigned short v) {
  return __uint_as_float((unsigned int)v << 16);
}

__device__ __forceinline__ int scan256_excl(int v, int buf[2][256], int t) {
  int cur = 0;
  buf[0][t] = v;
  __syncthreads();
  for (int off = 1; off < 256; off <<= 1) {
    int nxt = cur ^ 1;
    int s = buf[cur][t];
    if (t >= off) s += buf[cur][t - off];
    buf[nxt][t] = s;
    cur = nxt;
    __syncthreads();
  }
  return buf[cur][t] - v;
}

// ---------------------------------------------------------------------------
// K_WSPACK: pack sage weights B=[wl|wr] (128 x 256) into fragment order.
// Also zeroes accum.
// ---------------------------------------------------------------------------
__global__ __launch_bounds__(256) void k_wspack(const float* __restrict__ wl,
                                                const float* __restrict__ wr,
                                                unsigned short* __restrict__ wsp,
                                                float* __restrict__ accum) {
  int idx = blockIdx.x * 256 + threadIdx.x;     // 0..4095
  if (idx < HID) accum[idx] = 0.f;
  int lane = idx & 63;
  int n = (idx >> 6) & 7;
  int ks = idx >> 9;                            // 0..7
  int fr = lane & 15, kg = lane >> 4;
  int row = n * 16 + fr;
  int k0 = ks * 32 + kg * 8;
  const float* src = (k0 < HID) ? (wl + (size_t)row * HID + k0)
                                : (wr + (size_t)row * HID + (k0 - HID));
  float4 v0 = *(const float4*)(src);
  float4 v1 = *(const float4*)(src + 4);
  unsigned int* o = (unsigned int*)(wsp + (size_t)idx * 8);
  o[0] = pkbf(v0.x, v0.y);
  o[1] = pkbf(v0.z, v0.w);
  o[2] = pkbf(v1.x, v1.y);
  o[3] = pkbf(v1.z, v1.w);
}

// ---------------------------------------------------------------------------
// K_WPACK: pack proj weights (128 x 1024) into fragment order (R4, proven)
// ---------------------------------------------------------------------------
__global__ __launch_bounds__(256) void k_wpack(const float* __restrict__ w,
                                               unsigned short* __restrict__ wp) {
  int idx = blockIdx.x * 256 + threadIdx.x;   // 0..16383
  int lane = idx & 63;
  int n = (idx >> 6) & 7;
  int ks = idx >> 9;                          // 0..31
  int fr = lane & 15, kg = lane >> 4;
  const float* src = w + (size_t)(n * 16 + fr) * NODE_DIM + ks * 32 + kg * 8;
  float4 v0 = *(const float4*)(src);
  float4 v1 = *(const float4*)(src + 4);
  unsigned int* o = (unsigned int*)(wp + (size_t)idx * 8);
  o[0] = pkbf(v0.x, v0.y);
  o[1] = pkbf(v0.z, v0.w);
  o[2] = pkbf(v1.x, v1.y);
  o[3] = pkbf(v1.z, v1.w);
}

// ---------------------------------------------------------------------------
// CSR build (PROVEN 474-baseline path): hist -> scan -> scan -> scatter ->
// per-bucket CSR. Two-phase partition = contiguous write ranges per
// (block,bucket) cursor -> coalesced writes (R7's direct fill was 112 MB of
// partial-line RMW; this is the fix).
// ---------------------------------------------------------------------------
__global__ __launch_bounds__(256) void k_hist(const int* __restrict__ ei,
                                              int* __restrict__ counts) {
  __shared__ int bins[NBUCK];
  int t = threadIdx.x;
  if (t < NBUCK) bins[t] = 0;
  __syncthreads();
  int base = blockIdx.x * SHARD;
  for (int i = t; i < SHARD; i += 256)
    atomicAdd(&bins[ei[N_EDGES + base + i] >> 8], 1);
  __syncthreads();
  if (t < NBUCK) counts[t * 256 + blockIdx.x] = bins[t];
}

__global__ __launch_bounds__(256) void k_s1(const int* __restrict__ counts,
                                            int* __restrict__ basem,
                                            int* __restrict__ btot) {
  __shared__ int buf[2][256];
  int t = threadIdx.x, b = blockIdx.x;
  int v = counts[b * 256 + t];
  int excl = scan256_excl(v, buf, t);
  basem[b * 256 + t] = excl;
  if (t == 255) btot[b] = excl + v;
}

__global__ __launch_bounds__(256) void k_s2(const int* __restrict__ btot,
                                            int* __restrict__ bstart) {
  __shared__ int buf[2][256];
  int t = threadIdx.x;
  int v = (t < NBUCK) ? btot[t] : 0;
  int excl = scan256_excl(v, buf, t);
  if (t < NBUCK) bstart[t] = excl;
  if (t == 0) bstart[NBUCK] = N_EDGES;
}

__global__ __launch_bounds__(256) void k_scatter(const int* __restrict__ ei,
                                                 const int* __restrict__ basem,
                                                 const int* __restrict__ bstart,
                                                 unsigned int* __restrict__ bs) {
  __shared__ int cur[NBUCK];
  int t = threadIdx.x;
  if (t < NBUCK) cur[t] = bstart[t] + basem[t * 256 + blockIdx.x];
  __syncthreads();
  int base = blockIdx.x * SHARD;
  for (int i = t; i < SHARD; i += 256) {
    int e = base + i;
    unsigned int src = (unsigned int)ei[e];
    unsigned int dst = (unsigned int)ei[N_EDGES + e];
    int pos = atomicAdd(&cur[dst >> 8], 1);
    bs[pos] = src | ((dst & 255u) << 16);
  }
}

__global__ __launch_bounds__(256) void k_bucket(const int* __restrict__ bstart,
                                                const unsigned int* __restrict__ bs,
                                                unsigned short* __restrict__ nbr,
                                                int* __restrict__ offs,
                                                int* __restrict__ deg) {
  __shared__ int bins[256];
  __shared__ int buf[2][256];
  __shared__ int curs[256];
  int t = threadIdx.x, b = blockIdx.x;
  int s = bstart[b], e = bstart[b + 1];
  bins[t] = 0;
  __syncthreads();
  for (int i = s + t; i < e; i += 256)
    atomicAdd(&bins[(bs[i] >> 16) & 255u], 1);
  __syncthreads();
  int v = bins[t];
  int excl = scan256_excl(v, buf, t);
  int node = b * 256 + t;
  deg[node]  = v;
  offs[node] = s + excl;
  curs[t]    = s + excl;
  __syncthreads();
  for (int i = s + t; i < e; i += 256) {
    unsigned int p = bs[i];
    int pos = atomicAdd(&curs[(p >> 16) & 255u], 1);
    nbr[pos] = (unsigned short)(p & 0xffffu);
  }
}

// ---------------------------------------------------------------------------
// proj strip body (R4, proven): barrier-free register MFMA
// ---------------------------------------------------------------------------
__device__ __forceinline__ void proj_strip(const float* __restrict__ x,
                                           const unsigned short* __restrict__ wp,
                                           const float* __restrict__ pb,
                                           unsigned short* __restrict__ h,
                                           int strip, int lane) {
  const int fr = lane & 15, kg = lane >> 4;
  const int m0s = strip * 32;
  int r0 = m0s + fr;      if (r0 >= N_NODES) r0 = N_NODES - 1;
  int r1 = m0s + 16 + fr; if (r1 >= N_NODES) r1 = N_NODES - 1;
  const float* a0p = x + (size_t)r0 * NODE_DIM + kg * 8;
  const float* a1p = x + (size_t)r1 * NODE_DIM + kg * 8;
  const bf16x8* bp = (const bf16x8*)wp + lane;
  f32x4 acc[2][8] = {};
  float4 xa0, xa1, xa2, xa3, ya0, ya1, ya2, ya3;

#define LOADA_X(KS) { const float* p0 = a0p + (KS) * 32; const float* p1 = a1p + (KS) * 32; \
  xa0 = *(const float4*)p0; xa1 = *(const float4*)(p0 + 4); \
  xa2 = *(const float4*)p1; xa3 = *(const float4*)(p1 + 4); }
#define LOADA_Y(KS) { const float* p0 = a0p + (KS) * 32; const float* p1 = a1p + (KS) * 32; \
  ya0 = *(const float4*)p0; ya1 = *(const float4*)(p0 + 4); \
  ya2 = *(const float4*)p1; ya3 = *(const float4*)(p1 + 4); }
#define COMPUTE(A0, A1, A2, A3, KS) { \
  bf16x8 bfv[8]; \
  _Pragma("unroll") \
  for (int n = 0; n < 8; n++) bfv[n] = bp[((KS) * 8 + n) * 64]; \
  u32x4 pa0, pa1; \
  pa0[0] = pkbf(A0.x, A0.y); pa0[1] = pkbf(A0.z, A0.w); \
  pa0[2] = pkbf(A1.x, A1.y); pa0[3] = pkbf(A1.z, A1.w); \
  pa1[0] = pkbf(A2.x, A2.y); pa1[1] = pkbf(A2.z, A2.w); \
  pa1[2] = pkbf(A3.x, A3.y); pa1[3] = pkbf(A3.z, A3.w); \
  bf16x8 af0 = __builtin_bit_cast(bf16x8, pa0); \
  bf16x8 af1 = __builtin_bit_cast(bf16x8, pa1); \
  _Pragma("unroll") \
  for (int n = 0; n < 8; n++) { \
    acc[0][n] = __builtin_amdgcn_mfma_f32_16x16x32_bf16(af0, bfv[n], acc[0][n], 0, 0, 0); \
    acc[1][n] = __builtin_amdgcn_mfma_f32_16x16x32_bf16(af1, bfv[n], acc[1][n], 0, 0, 0); \
  } }

  LOADA_X(0);
  for (int ks = 0; ks < 32; ks += 2) {
    LOADA_Y(ks + 1);
    COMPUTE(xa0, xa1, xa2, xa3, ks);
    if (ks + 2 < 32) LOADA_X(ks + 2);
    COMPUTE(ya0, ya1, ya2, ya3, ks + 1);
  }
#undef LOADA_X
#undef LOADA_Y
#undef COMPUTE

  const int cr = (lane >> 4) * 4, cc = lane & 15;
#pragma unroll
  for (int n = 0; n < 8; n++) {
    const int col = n * 16 + cc;
    const float bias = pb[col];
#pragma unroll
    for (int m = 0; m < 2; m++) {
      const int rowb = m0s + m * 16 + cr;
#pragma unroll
      for (int i = 0; i < 4; i++) {
        float v = acc[m][n][i] + bias;
        h[(size_t)(rowb + i) * HID + col] = f2bf(v > 0.f ? v : 0.f);
      }
    }
  }
}

__global__ __launch_bounds__(256, 3) void k_proj(const float* __restrict__ x,
                                                 const unsigned short* __restrict__ wp,
                                                 const float* __restrict__ pb,
                                                 unsigned short* __restrict__ h) {
  proj_strip(x, wp, pb, h, blockIdx.x * 4 + (threadIdx.x >> 6), threadIdx.x & 63);
}

// ---------------------------------------------------------------------------
// K_GATHER: mean over neighbors, 4-deep ILP (16 rows in flight per wave).
// Covers PAD nodes (deg 0 -> writes zeros) so sage needs no guards on mn.
// ---------------------------------------------------------------------------
__global__ __launch_bounds__(256) void k_gather(const unsigned short* __restrict__ h,
                                                const unsigned short* __restrict__ nbr,
                                                const int* __restrict__ offs,
                                                const int* __restrict__ deg,
                                                unsigned short* __restrict__ mn) {
  const int wave = threadIdx.x >> 6;
  const int lane = threadIdx.x & 63;
  const int node = blockIdx.x * 4 + wave;        // < PAD by grid
  const int g = lane >> 4, li = lane & 15;
  const int d  = deg[node];
  const int st = offs[node];
  float a[8] = {0.f, 0.f, 0.f, 0.f, 0.f, 0.f, 0.f, 0.f};
  int n = g;
  for (; n + 12 < d; n += 16) {
    int s0 = nbr[st + n];
    int s1 = nbr[st + n + 4];
    int s2 = nbr[st + n + 8];
    int s3 = nbr[st + n + 12];
    u16x8 v0 = *(const u16x8*)(h + (size_t)s0 * HID + li * 8);
    u16x8 v1 = *(const u16x8*)(h + (size_t)s1 * HID + li * 8);
    u16x8 v2 = *(const u16x8*)(h + (size_t)s2 * HID + li * 8);
    u16x8 v3 = *(const u16x8*)(h + (size_t)s3 * HID + li * 8);
#pragma unroll
    for (int k = 0; k < 8; k++)
      a[k] += (bf2f(v0[k]) + bf2f(v1[k])) + (bf2f(v2[k]) + bf2f(v3[k]));
  }
  for (; n < d; n += 4) {
    int s0 = nbr[st + n];
    u16x8 v0 = *(const u16x8*)(h + (size_t)s0 * HID + li * 8);
#pragma unroll
    for (int k = 0; k < 8; k++) a[k] += bf2f(v0[k]);
  }
#pragma unroll
  for (int k = 0; k < 8; k++) {
    a[k] += __shfl_xor(a[k], 16);
    a[k] += __shfl_xor(a[k], 32);
  }
  if (g == 0) {
    float inv = 1.f / fmaxf((float)d, 1.f);
    u16x8 r;
#pragma unroll
    for (int k = 0; k < 8; k++) r[k] = f2bf(a[k] * inv);
    *(u16x8*)(mn + (size_t)node * HID + li * 8) = r;
  }
}

// ---------------------------------------------------------------------------
// K_SAGE (R7, kept): barrier-free register MFMA + in-register LayerNorm.
// ---------------------------------------------------------------------------
__global__ __launch_bounds__(256) void k_sage(const unsigned short* __restrict__ mn,
                                              const unsigned short* __restrict__ h,
                                              const unsigned short* __restrict__ wsp,
                                              const float* __restrict__ lb,
                                              const float* __restrict__ lg,
                                              const float* __restrict__ lbt,
                                              float* __restrict__ accum) {
  __shared__ float red[4][128];
  const int wave = threadIdx.x >> 6, lane = threadIdx.x & 63;
  const int strip = blockIdx.x * 4 + wave;   // 0..PSTRIPS-1
  const int m0s = strip * 32;
  const int fr = lane & 15, kg = lane >> 4;
  const bf16x8* bp = (const bf16x8*)wsp + lane;

  const unsigned short* a0m = mn + (size_t)(m0s + fr) * HID + kg * 8;
  const unsigned short* a1m = mn + (size_t)(m0s + 16 + fr) * HID + kg * 8;
  const unsigned short* a0h = h  + (size_t)(m0s + fr) * HID + kg * 8;
  const unsigned short* a1h = h  + (size_t)(m0s + 16 + fr) * HID + kg * 8;

  f32x4 acc[2][8] = {};
#pragma unroll
  for (int ks = 0; ks < 8; ks++) {
    const unsigned short* s0 = (ks < 4) ? (a0m + ks * 32) : (a0h + (ks - 4) * 32);
    const unsigned short* s1 = (ks < 4) ? (a1m + ks * 32) : (a1h + (ks - 4) * 32);
    bf16x8 af0 = *(const bf16x8*)s0;
    bf16x8 af1 = *(const bf16x8*)s1;
    bf16x8 bfv[8];
#pragma unroll
    for (int n = 0; n < 8; n++) bfv[n] = bp[(ks * 8 + n) * 64];
#pragma unroll
    for (int n = 0; n < 8; n++) {
      acc[0][n] = __builtin_amdgcn_mfma_f32_16x16x32_bf16(af0, bfv[n], acc[0][n], 0, 0, 0);
      acc[1][n] = __builtin_amdgcn_mfma_f32_16x16x32_bf16(af1, bfv[n], acc[1][n], 0, 0, 0);
    }
  }

  const int cr = (lane >> 4) * 4, cc = lane & 15;
  float gv[8], bv[8], lbv[8];
#pragma unroll
  for (int n = 0; n < 8; n++) {
    gv[n]  = lg[n * 16 + cc];
    bv[n]  = lbt[n * 16 + cc];
    lbv[n] = lb[n * 16 + cc];
  }
  float pool[8] = {0.f, 0.f, 0.f, 0.f, 0.f, 0.f, 0.f, 0.f};
#pragma unroll
  for (int m = 0; m < 2; m++) {
#pragma unroll
    for (int i = 0; i < 4; i++) {
      float v[8];
      float sum = 0.f, ss = 0.f;
#pragma unroll
      for (int n = 0; n < 8; n++) {
        v[n] = acc[m][n][i] + lbv[n];
        sum += v[n];
        ss  += v[n] * v[n];
      }
#pragma unroll
      for (int off = 1; off < 16; off <<= 1) {
        sum += __shfl_xor(sum, off);
        ss  += __shfl_xor(ss, off);
      }
      float mu   = sum * (1.f / HID);
      float var  = ss * (1.f / HID) - mu * mu;
      float rinv = rsqrtf(var + LN_EPS);
      int row = m0s + m * 16 + cr + i;
      if (row < N_NODES) {
#pragma unroll
        for (int n = 0; n < 8; n++) {
          float y = (v[n] - mu) * rinv * gv[n] + bv[n];
          pool[n] += fmaxf(y, 0.f);
        }
      }
    }
  }
#pragma unroll
  for (int n = 0; n < 8; n++) {
    pool[n] += __shfl_xor(pool[n], 16);
    pool[n] += __shfl_xor(pool[n], 32);
  }
  if (lane < 16) {
#pragma unroll
    for (int n = 0; n < 8; n++) red[wave][n * 16 + lane] = pool[n];
  }
  __syncthreads();
  if (wave == 0) {
    float s0 = red[0][lane] + red[1][lane] + red[2][lane] + red[3][lane];
    float s1 = red[0][lane + 64] + red[1][lane + 64] + red[2][lane + 64] + red[3][lane + 64];
    atomicAdd(&accum[lane], s0);
    atomicAdd(&accum[lane + 64], s1);
  }
}

// ---------------------------------------------------------------------------
__global__ __launch_bounds__(128) void k_final(const float* __restrict__ accum,
                                               const float* __restrict__ ow,
                                               const float* __restrict__ ob,
                                               float* __restrict__ out) {
  __shared__ float gs[HID];
  int t = threadIdx.x;
  gs[t] = accum[t] * (1.f / N_NODES);
  __syncthreads();
  float s = ob[t];
  for (int k = 0; k < HID; k++) s += gs[k] * ow[t * HID + k];
  out[t] = s;
}

// ---------------------------------------------------------------------------
extern "C" void kernel_launch(void* const* d_in, const int* in_sizes, int n_in,
                              void* d_out, int out_size, void* d_ws, size_t ws_size,
                              hipStream_t stream) {
  const float* x   = (const float*)d_in[0];
  const int*   ei  = (const int*)d_in[1];
  const float* pw  = (const float*)d_in[2];
  const float* pb  = (const float*)d_in[3];
  const float* wl  = (const float*)d_in[4];
  const float* lb  = (const float*)d_in[5];
  const float* wr  = (const float*)d_in[6];
  const float* lg  = (const float*)d_in[7];
  const float* lbt = (const float*)d_in[8];
  const float* ow  = (const float*)d_in[9];
  const float* ob  = (const float*)d_in[10];
  float* out = (float*)d_out;

  unsigned short* h  = (unsigned short*)d_ws;                   // PAD*128 bf16
  unsigned short* mn = h + (size_t)PAD * HID;                   // PAD*128 bf16
  unsigned int* bsp  = (unsigned int*)(mn + (size_t)PAD * HID); // E packed u32
  unsigned short* nbr = (unsigned short*)(bsp + N_EDGES);       // E u16
  int* counts = (int*)(nbr + N_EDGES);                          // NBUCK*256
  int* basem  = counts + NBUCK * 256;                           // NBUCK*256
  int* btot   = basem + NBUCK * 256;                            // 256
  int* bstart = btot + 256;                                     // 256+1
  int* offs   = bstart + 260;                                   // PAD
  int* deg    = offs + PAD;                                     // PAD
  float* accum = (float*)(deg + PAD);                           // 128
  unsigned short* wp  = (unsigned short*)(accum + 128);         // 128*1024 bf16 packed
  unsigned short* wsp = wp + (size_t)HID * NODE_DIM;            // 128*256 bf16 packed

  hipLaunchKernelGGL(k_wspack,  dim3(16),        dim3(256), 0, stream, wl, wr, wsp, accum);
  hipLaunchKernelGGL(k_wpack,   dim3(64),        dim3(256), 0, stream, pw, wp);
  hipLaunchKernelGGL(k_hist,    dim3(256),       dim3(256), 0, stream, ei, counts);
  hipLaunchKernelGGL(k_s1,      dim3(NBUCK),     dim3(256), 0, stream, counts, basem, btot);
  hipLaunchKernelGGL(k_s2,      dim3(1),         dim3(256), 0, stream, btot, bstart);
  hipLaunchKernelGGL(k_scatter, dim3(256),       dim3(256), 0, stream, ei, basem, bstart, bsp);
  hipLaunchKernelGGL(k_bucket,  dim3(NBUCK),     dim3(256), 0, stream, bstart, bsp, nbr, offs, deg);
  hipLaunchKernelGGL(k_proj,    dim3(PSTRIPS/4), dim3(256), 0, stream, x, wp, pb, h);
  hipLaunchKernelGGL(k_gather,  dim3(PAD/4),     dim3(256), 0, stream, h, nbr, offs, deg, mn);
  hipLaunchKernelGGL(k_sage,    dim3(PSTRIPS/4), dim3(256), 0, stream, mn, h, wsp, lb, lg, lbt, accum);
  hipLaunchKernelGGL(k_final,   dim3(1),         dim3(128), 0, stream, accum, ow, ob, out);
}